// Round 9
// baseline (916.460 us; speedup 1.0000x reference)
//
#include <hip/hip_runtime.h>

typedef unsigned short u16;
typedef __attribute__((ext_vector_type(8))) __bf16 bf16x8;
typedef __attribute__((ext_vector_type(4))) float f32x4;
typedef __attribute__((ext_vector_type(4))) unsigned int u32x4;

#define MFMA16(a, b, c) __builtin_amdgcn_mfma_f32_16x16x32_bf16(a, b, c, 0, 0, 0)

__device__ __forceinline__ u16 f2bf(float f) {
    unsigned u = __float_as_uint(f);
    u = (u + 0x7FFFu + ((u >> 16) & 1u)) >> 16;
    return (u16)u;
}

// async global->LDS, 16B per lane; LDS dest = wave-uniform base + lane*16
__device__ __forceinline__ void gl_lds16(const u16* g, u16* l) {
    __builtin_amdgcn_global_load_lds(
        (const __attribute__((address_space(1))) unsigned int*)g,
        (__attribute__((address_space(3))) unsigned int*)l, 16, 0, 0);
}

static constexpr int Bv = 2, Tv = 2048, Cv = 1024, Hv = 16, Dv = 64;
static constexpr int Mv = Bv * Tv; // 4096
static constexpr unsigned NBLK = 512;

// ws element offsets (u16 elements)
static constexpr size_t OFF_XB = 0;                      // x bf16       [4096,1024]
static constexpr size_t OFF_WQ = 4194304;                // Wq bf16      [1024,1024]
static constexpr size_t OFF_WK = OFF_WQ + 1048576;
static constexpr size_t OFF_WV = OFF_WK + 1048576;
static constexpr size_t OFF_WO = OFF_WV + 1048576;
static constexpr size_t OFF_Q  = OFF_WO + 1048576;       // Q bf16 [M, C]
static constexpr size_t OFF_K  = OFF_Q + 4194304;        // K bf16 [M, C]
static constexpr size_t OFF_VT = OFF_K + 4194304;        // V^T bf16 [C, M]
static constexpr size_t OFF_A  = OFF_VT + 4194304;       // attended bf16 [M, C]
static constexpr size_t OFF_CNT_BYTES = (OFF_A + 4194304) * 2;  // barrier counters (bytes)

// software grid barrier: all 512 blocks co-resident by construction
// (68KB LDS -> 2 blocks/CU; 8 waves/block -> 16/CU; VGPR capped 128 by launch_bounds)
__device__ __forceinline__ void gridbar(unsigned* cnt, unsigned target) {
    __threadfence();                 // release this block's global writes
    __syncthreads();
    if (threadIdx.x == 0) {
        __hip_atomic_fetch_add(cnt, 1u, __ATOMIC_ACQ_REL, __HIP_MEMORY_SCOPE_AGENT);
        while (__hip_atomic_load(cnt, __ATOMIC_ACQUIRE, __HIP_MEMORY_SCOPE_AGENT) < target) {
            __builtin_amdgcn_s_sleep(2);
        }
    }
    __syncthreads();
    __threadfence();                 // acquire: fresh reads after barrier
}

// LDS overlay: one allocation shared by all phases (68 KB -> 2 blocks/CU)
union SMem {
    struct { u16 lA[2][128 * 64]; u16 lB[2][128 * 64]; } p1;                   // 64 KB
    struct { u16 lK[2][64 * 64]; u16 lVT[2][64 * 64]; u16 lP[8][32][72]; } p2; // 68 KB
    struct { u16 lA[2][128 * 64]; u16 lB[2][64 * 64]; } p3;                    // 48 KB
};

// ---------------- 128x128-tile bf16 GEMM (half-block: 256 thr), BK=64, swizzled ----------------
template <bool ROWBIAS>
__device__ __forceinline__ void gemm_half(
    u16* __restrict__ lA, u16* __restrict__ lB,
    const u16* __restrict__ A, const u16* __restrict__ Wt,
    const float* __restrict__ bias, u16* __restrict__ outp,
    int m0, int n0, int N, int K)
{
    const int tid  = threadIdx.x & 255;
    const int lane = tid & 63, w = tid >> 6;
    const int quad = lane >> 4, lm = lane & 15;
    const int wm = (w & 1) * 64, wn = (w >> 1) * 64;

    f32x4 zero = {0.f, 0.f, 0.f, 0.f};
    f32x4 acc[4][4];
    #pragma unroll
    for (int mt = 0; mt < 4; mt++)
        #pragma unroll
        for (int nt = 0; nt < 4; nt++) acc[mt][nt] = zero;

    const int rowi = lane >> 3, seg = lane & 7;

    for (int k0 = 0; k0 < K; k0 += 64) {
        #pragma unroll
        for (int i = 0; i < 4; i++) {
            int rbase = w * 32 + i * 8;
            int row = rbase + rowi;
            int gseg = seg ^ (row & 7);
            gl_lds16(A  + (size_t)(m0 + row) * K + k0 + gseg * 8, &lA[rbase * 64]);
            gl_lds16(Wt + (size_t)(n0 + row) * K + k0 + gseg * 8, &lB[rbase * 64]);
        }
        __syncthreads();
        #pragma unroll
        for (int ks = 0; ks < 2; ks++) {
            const int swz = ((ks * 4 + quad) ^ (lm & 7)) * 8;
            bf16x8 af[4], bf[4];
            #pragma unroll
            for (int mt = 0; mt < 4; mt++)
                af[mt] = *(const bf16x8*)&lA[(wm + mt * 16 + lm) * 64 + swz];
            #pragma unroll
            for (int nt = 0; nt < 4; nt++)
                bf[nt] = *(const bf16x8*)&lB[(wn + nt * 16 + lm) * 64 + swz];
            #pragma unroll
            for (int mt = 0; mt < 4; mt++)
                #pragma unroll
                for (int nt = 0; nt < 4; nt++)
                    acc[mt][nt] = MFMA16(af[mt], bf[nt], acc[mt][nt]);
        }
        __syncthreads();
    }

    float rb[4][4];
    if (ROWBIAS) {
        #pragma unroll
        for (int mt = 0; mt < 4; mt++)
            #pragma unroll
            for (int r = 0; r < 4; r++)
                rb[mt][r] = bias[m0 + wm + mt * 16 + quad * 4 + r];
    }

    #pragma unroll
    for (int nt = 0; nt < 4; nt++) {
        int col = n0 + wn + nt * 16 + lm;
        float cb = ROWBIAS ? 0.f : bias[col];
        #pragma unroll
        for (int mt = 0; mt < 4; mt++) {
            #pragma unroll
            for (int r = 0; r < 4; r++) {
                int row = m0 + wm + mt * 16 + quad * 4 + r;
                outp[(size_t)row * N + col] = f2bf(acc[mt][nt][r] + (ROWBIAS ? rb[mt][r] : cb));
            }
        }
    }
}

// ---------------- fused pipeline (regular launch + software grid barrier) ----------------
__global__ __launch_bounds__(512, 4) void fused(
    const float* __restrict__ x,
    const float* __restrict__ Wq, const float* __restrict__ Wk,
    const float* __restrict__ Wv, const float* __restrict__ Wo,
    const float* __restrict__ bq, const float* __restrict__ bk,
    const float* __restrict__ bv, const float* __restrict__ bo,
    u16* __restrict__ ws, float* __restrict__ out, unsigned* __restrict__ cnt)
{
    __shared__ SMem sm;

    // ======== phase 0: fp32 -> bf16 convert (x + 4 weights) ========
    {
        int t0 = blockIdx.x * 512 + threadIdx.x;
        #pragma unroll
        for (int it = 0; it < 8; it++) {
            int idx = (t0 + it * 262144) * 4;
            const float* src; int off;
            if (idx < 4194304) { src = x; off = idx; }
            else {
                int rel = idx - 4194304;
                int j = rel >> 20;
                off = rel & 1048575;
                src = (j == 0) ? Wq : (j == 1) ? Wk : (j == 2) ? Wv : Wo;
            }
            float4 v = *(const float4*)(src + off);
            ushort4 o;
            o.x = f2bf(v.x); o.y = f2bf(v.y); o.z = f2bf(v.z); o.w = f2bf(v.w);
            *(ushort4*)(ws + idx) = o;
        }
    }
    gridbar(cnt + 0, NBLK);

    // ======== phase 1: QKV projections (768 half-block jobs, 3 per CU-pair) ========
    {
        const int b = blockIdx.x;
        const int is_upper = b >> 8, pairp = b & 255;
        const int halfid = threadIdx.x >> 8;
        const int slot = is_upper * 2 + halfid;
        if (slot < 3) {
            int j = pairp * 3 + slot;          // 0..767
            int which = j >> 8, rem = j & 255;
            u16* lA = sm.p1.lA[halfid];
            u16* lB = sm.p1.lB[halfid];
            if (which == 0)
                gemm_half<false>(lA, lB, ws + OFF_XB, ws + OFF_WQ, bq, ws + OFF_Q,
                                 (rem >> 3) * 128, (rem & 7) * 128, Cv, Cv);
            else if (which == 1)
                gemm_half<false>(lA, lB, ws + OFF_XB, ws + OFF_WK, bk, ws + OFF_K,
                                 (rem >> 3) * 128, (rem & 7) * 128, Cv, Cv);
            else  // V^T = Wv @ x^T: rows = channel, cols = token, bias by row
                gemm_half<true>(lA, lB, ws + OFF_WV, ws + OFF_XB, bv, ws + OFF_VT,
                                (rem & 7) * 128, (rem >> 3) * 128, Mv, Cv);
        } else {
            for (int k0 = 0; k0 < Cv; k0 += 64) { __syncthreads(); __syncthreads(); }
        }
    }
    gridbar(cnt + 1, NBLK);

    // ======== phase 2: flash attention (key-split wave-groups, R6 body) ========
    {
        const u16* Qp  = ws + OFF_Q;
        const u16* Kp  = ws + OFF_K;
        const u16* VTg = ws + OFF_VT;
        u16* Op = ws + OFF_A;

        const int tid  = threadIdx.x;
        const int lane = tid & 63, w = tid >> 6;
        const int g = w >> 2, wl = w & 3;
        const int quad = lane >> 4, lm = lane & 15;

        const int idx  = blockIdx.x;
        const int half = idx >> 8;
        const int grp  = idx & 255;
        const int bh   = (half << 4) | (grp >> 4);
        const int j    = grp & 15;
        const int qt   = half ? j : 15 - j;
        const int h = bh & 15, b = bh >> 4;

        const int qb = qt * 128;
        const size_t headoff = (size_t)b * Tv * Cv + (size_t)h * Dv;
        const size_t vthead  = (size_t)h * 64 * Mv + (size_t)b * Tv;

        bf16x8 qf[2][2];
        #pragma unroll
        for (int nt = 0; nt < 2; nt++) {
            const u16* qptr = Qp + headoff + (size_t)(qb + wl * 32 + nt * 16 + lm) * Cv + quad * 8;
            qf[0][nt] = *(const bf16x8*)(qptr);
            qf[1][nt] = *(const bf16x8*)(qptr + 32);
        }

        f32x4 zero = {0.f, 0.f, 0.f, 0.f};
        f32x4 oacc[2][4];
        #pragma unroll
        for (int mt = 0; mt < 2; mt++)
            #pragma unroll
            for (int nt = 0; nt < 4; nt++) oacc[mt][nt] = zero;
        float Lp[2] = {0.f, 0.f};

        const float SC = 0.18033688011112042f;  // (1/sqrt(64)) * log2(e)
        const int rowi = lane >> 3, seg = lane & 7;

        auto stage = [&](int kt) {
            const int k0 = kt * 64;
            #pragma unroll
            for (int hf = 0; hf < 2; hf++) {
                int rbase = wl * 16 + hf * 8;
                int row = rbase + rowi;
                int gseg = seg ^ (row & 7);
                gl_lds16(Kp + headoff + (size_t)(k0 + row) * Cv + gseg * 8, &sm.p2.lK[g][rbase * 64]);
                gl_lds16(VTg + vthead + (size_t)row * Mv + k0 + gseg * 8, &sm.p2.lVT[g][rbase * 64]);
            }
        };

        auto body = [&](int kt, bool domask) __attribute__((always_inline)) {
            const int k0 = kt * 64;
            f32x4 stt[4][2];
            #pragma unroll
            for (int mt = 0; mt < 4; mt++)
                #pragma unroll
                for (int nt = 0; nt < 2; nt++) stt[mt][nt] = zero;
            #pragma unroll
            for (int ks = 0; ks < 2; ks++) {
                #pragma unroll
                for (int mt = 0; mt < 4; mt++) {
                    bf16x8 kf = *(const bf16x8*)
                        &sm.p2.lK[g][(mt * 16 + lm) * 64 + (((ks * 4 + quad) ^ (lm & 7)) * 8)];
                    #pragma unroll
                    for (int nt = 0; nt < 2; nt++)
                        stt[mt][nt] = MFMA16(kf, qf[ks][nt], stt[mt][nt]);
                }
            }
            #pragma unroll
            for (int mt = 0; mt < 4; mt++) {
                #pragma unroll
                for (int nt = 0; nt < 2; nt++) {
                    const int keyb = k0 + mt * 16 + quad * 4;
                    const int qrow = qb + wl * 32 + nt * 16 + lm;
                    float e0 = __builtin_amdgcn_exp2f(fmaf(stt[mt][nt][0], SC, -16.f));
                    float e1 = __builtin_amdgcn_exp2f(fmaf(stt[mt][nt][1], SC, -16.f));
                    float e2 = __builtin_amdgcn_exp2f(fmaf(stt[mt][nt][2], SC, -16.f));
                    float e3 = __builtin_amdgcn_exp2f(fmaf(stt[mt][nt][3], SC, -16.f));
                    if (domask) {
                        if (keyb + 0 > qrow) e0 = 0.f;
                        if (keyb + 1 > qrow) e1 = 0.f;
                        if (keyb + 2 > qrow) e2 = 0.f;
                        if (keyb + 3 > qrow) e3 = 0.f;
                    }
                    Lp[nt] += e0 + e1 + e2 + e3;
                    ushort4 pk;
                    pk.x = (u16)(__float_as_uint(e0) >> 16);
                    pk.y = (u16)(__float_as_uint(e1) >> 16);
                    pk.z = (u16)(__float_as_uint(e2) >> 16);
                    pk.w = (u16)(__float_as_uint(e3) >> 16);
                    *(ushort4*)&sm.p2.lP[w][nt * 16 + lm][mt * 16 + quad * 4] = pk;
                }
            }
            #pragma unroll
            for (int ks = 0; ks < 2; ks++) {
                bf16x8 pf[2];
                #pragma unroll
                for (int mt = 0; mt < 2; mt++)
                    pf[mt] = *(const bf16x8*)&sm.p2.lP[w][mt * 16 + lm][ks * 32 + quad * 8];
                #pragma unroll
                for (int nt = 0; nt < 4; nt++) {
                    bf16x8 vf = *(const bf16x8*)
                        &sm.p2.lVT[g][(nt * 16 + lm) * 64 + (((ks * 4 + quad) ^ (lm & 7)) * 8)];
                    #pragma unroll
                    for (int mt = 0; mt < 2; mt++)
                        oacc[mt][nt] = MFMA16(pf[mt], vf, oacc[mt][nt]);
                }
            }
        };

        for (int i = 0; i < qt; i++) {
            if (i) __syncthreads();
            stage(2 * i + g);
            __syncthreads();
            body(2 * i + g, false);
        }
        if (qt) __syncthreads();
        stage(2 * qt + g);
        __syncthreads();
        body(2 * qt + g, true);
        __syncthreads();

        // merge group partials through LDS (reuse lP as f32 buffer)
        float* lO = (float*)&sm.p2.lP[0][0][0];      // [32 slots][256 lanes]
        float* lL = lO + 32 * 256;                   // [2][256]
        const int t = tid & 255;
        if (g == 1) {
            #pragma unroll
            for (int mt = 0; mt < 2; mt++)
                #pragma unroll
                for (int nt = 0; nt < 4; nt++)
                    #pragma unroll
                    for (int r = 0; r < 4; r++)
                        lO[(mt * 16 + nt * 4 + r) * 256 + t] = oacc[mt][nt][r];
            lL[t] = Lp[0];
            lL[256 + t] = Lp[1];
        }
        __syncthreads();
        if (g == 0) {
            #pragma unroll
            for (int mt = 0; mt < 2; mt++)
                #pragma unroll
                for (int nt = 0; nt < 4; nt++)
                    #pragma unroll
                    for (int r = 0; r < 4; r++)
                        oacc[mt][nt][r] += lO[(mt * 16 + nt * 4 + r) * 256 + t];
            Lp[0] += lL[t];
            Lp[1] += lL[256 + t];

            float Lred[2];
            #pragma unroll
            for (int nt = 0; nt < 2; nt++) {
                float L = Lp[nt];
                L += __shfl_xor(L, 16, 64);
                L += __shfl_xor(L, 32, 64);
                Lred[nt] = 1.0f / L;
            }
            #pragma unroll
            for (int mt = 0; mt < 2; mt++) {
                float inv[4];
                #pragma unroll
                for (int r = 0; r < 4; r++)
                    inv[r] = __shfl(Lred[mt], (lane & 48) | (quad * 4 + r), 64);
                #pragma unroll
                for (int nt = 0; nt < 4; nt++) {
                    #pragma unroll
                    for (int r = 0; r < 4; r++) {
                        int row = qb + wl * 32 + mt * 16 + quad * 4 + r;
                        Op[headoff + (size_t)row * Cv + nt * 16 + lm] = f2bf(oacc[mt][nt][r] * inv[r]);
                    }
                }
            }
        }
    }
    gridbar(cnt + 2, NBLK);

    // ======== phase 3: output projection (512 half-block jobs of 128x64) ========
    {
        const int b = blockIdx.x;
        if (b < 256) {
            const int halfid = threadIdx.x >> 8;
            const int j = b * 2 + halfid;              // 0..511
            const int m0 = (j >> 4) * 128, n0 = (j & 15) * 64;
            u16* lA = sm.p3.lA[halfid];
            u16* lB = sm.p3.lB[halfid];
            const u16* A  = ws + OFF_A;
            const u16* Wt = ws + OFF_WO;

            const int tid  = threadIdx.x & 255;
            const int lane = tid & 63, w = tid >> 6;
            const int quad = lane >> 4, lm = lane & 15;
            const int K = Cv;

            f32x4 zero = {0.f, 0.f, 0.f, 0.f};
            f32x4 acc[2][4];
            #pragma unroll
            for (int mt = 0; mt < 2; mt++)
                #pragma unroll
                for (int nt = 0; nt < 4; nt++) acc[mt][nt] = zero;

            const int rowi = lane >> 3, seg = lane & 7;

            for (int k0 = 0; k0 < K; k0 += 64) {
                #pragma unroll
                for (int i = 0; i < 4; i++) {
                    int rbase = w * 32 + i * 8;
                    int row = rbase + rowi;
                    int gseg = seg ^ (row & 7);
                    gl_lds16(A + (size_t)(m0 + row) * K + k0 + gseg * 8, &lA[rbase * 64]);
                }
                {
                    int rbase = w * 16, row0 = rbase + rowi, row1 = row0 + 8;
                    gl_lds16(Wt + (size_t)(n0 + row0) * K + k0 + (seg ^ (row0 & 7)) * 8, &lB[rbase * 64]);
                    gl_lds16(Wt + (size_t)(n0 + row1) * K + k0 + (seg ^ (row1 & 7)) * 8, &lB[(rbase + 8) * 64]);
                }
                __syncthreads();
                #pragma unroll
                for (int ks = 0; ks < 2; ks++) {
                    const int swz = ((ks * 4 + quad) ^ (lm & 7)) * 8;
                    bf16x8 af[2], bf[4];
                    #pragma unroll
                    for (int mt = 0; mt < 2; mt++)
                        af[mt] = *(const bf16x8*)&lA[(w * 32 + mt * 16 + lm) * 64 + swz];
                    #pragma unroll
                    for (int nt = 0; nt < 4; nt++)
                        bf[nt] = *(const bf16x8*)&lB[(nt * 16 + lm) * 64 + swz];
                    #pragma unroll
                    for (int mt = 0; mt < 2; mt++)
                        #pragma unroll
                        for (int nt = 0; nt < 4; nt++)
                            acc[mt][nt] = MFMA16(af[mt], bf[nt], acc[mt][nt]);
                }
                __syncthreads();
            }

            #pragma unroll
            for (int nt = 0; nt < 4; nt++) {
                int col = n0 + nt * 16 + lm;
                float bvv = bo[col];
                #pragma unroll
                for (int mt = 0; mt < 2; mt++) {
                    #pragma unroll
                    for (int r = 0; r < 4; r++) {
                        int row = m0 + w * 32 + mt * 16 + quad * 4 + r;
                        out[(size_t)row * Cv + col] = acc[mt][nt][r] + bvv;
                    }
                }
            }
        }
    }
}

// ---------------- launcher ----------------
extern "C" void kernel_launch(void* const* d_in, const int* in_sizes, int n_in,
                              void* d_out, int out_size, void* d_ws, size_t ws_size,
                              hipStream_t stream) {
    const float* x  = (const float*)d_in[0];
    const float* Wq = (const float*)d_in[1];
    const float* bq = (const float*)d_in[2];
    const float* Wk = (const float*)d_in[3];
    const float* bk = (const float*)d_in[4];
    const float* Wv = (const float*)d_in[5];
    const float* bv = (const float*)d_in[6];
    const float* Wo = (const float*)d_in[7];
    const float* bo = (const float*)d_in[8];
    u16* ws = (u16*)d_ws;
    float* out = (float*)d_out;
    unsigned* cnt = (unsigned*)((char*)d_ws + OFF_CNT_BYTES);

    // zero the grid-barrier counters (ws is re-poisoned 0xAA before every launch)
    hipMemsetAsync(cnt, 0, 256, stream);

    fused<<<NBLK, 512, 0, stream>>>(x, Wq, Wk, Wv, Wo, bq, bk, bv, bo, ws, out, cnt);
}